// Round 2
// baseline (4799.490 us; speedup 1.0000x reference)
//
#include <hip/hip_runtime.h>

typedef __bf16 bf16_t;
typedef bf16_t bf16x8 __attribute__((ext_vector_type(8)));
typedef float  f32x4  __attribute__((ext_vector_type(4)));

#define TT 512
#define BB 1024

// packed weight chunk bases (16B chunks). Layer k: [N,K] row-major source.
#define cL0   0      // enc1_s  N=128 K=64   (folded We1a*Wphi_s)
#define cL1   1024   // enc1_h  N=128 K=128  (We1[:,128:])
#define cL2   3072   // enc2    N=128 K=128
#define cL3   5120   // pri1    N=128 K=128
#define cL4   7168   // pri2    N=128 K=128
#define cL5   9216   // dec1_z  N=128 K=64   (folded Wd1a*Wphi_z)
#define cL6   10240  // dec1_h  N=128 K=128  (Wd1[:,128:])
#define cL7   12288  // dec2    N=64  K=128
#define cL8   13312  // gates_s N=512 K=64   (folded Wih_a*Wphi_s)
#define cL9   17408  // gates_z N=512 K=64   (folded Wih_b*Wphi_z)
#define cL10  21504  // gates_h N=512 K=128  (W_hh)
#define NCHUNK 29696

#define WS_FBIAS_OFF 475136   // bytes: 768 floats (b_enc1[128], b_dec1[128], b_g[512])
#define WS_FOLD_OFF  478208   // bytes: 81920 floats (A_es, A_ds, G_s, G_z)

__device__ __forceinline__ f32x4 mfma16(bf16x8 a, bf16x8 b, f32x4 c) {
  return __builtin_amdgcn_mfma_f32_16x16x32_bf16(a, b, c, 0, 0, 0);
}
__device__ __forceinline__ float sigm(float x) { return 1.0f / (1.0f + __expf(-x)); }
__device__ __forceinline__ float tanh_f(float x) {
  x = fminf(fmaxf(x, -15.0f), 15.0f);
  float e = __expf(2.0f * x);
  return (e - 1.0f) / (e + 1.0f);
}
__device__ __forceinline__ float softplus_f(float x) {
  return (x > 15.0f) ? x : __logf(1.0f + __expf(x));
}
// LDS-only barrier: does NOT drain vmcnt (global loads into registers get
// compiler-inserted vmcnt waits at their USE, not at the barrier).
__device__ __forceinline__ void wg_barrier() {
  asm volatile("s_waitcnt lgkmcnt(0)\n\ts_barrier" ::: "memory");
}

// ---------------- setup kernel 1: fold phi layers into downstream weights ----------------
__global__ void vrnn_fold(const float* __restrict__ We1, const float* __restrict__ Wd1,
                          const float* __restrict__ Wih,
                          const float* __restrict__ Wps, const float* __restrict__ Wpz,
                          const float* __restrict__ bps, const float* __restrict__ bpz,
                          const float* __restrict__ be1, const float* __restrict__ bd1,
                          const float* __restrict__ bih, const float* __restrict__ bhh,
                          float* __restrict__ fold, float* __restrict__ fbias) {
  int id = blockIdx.x * 256 + threadIdx.x;
  if (id < 8192) {                                  // A_es = We1[:, :128] @ Wphi_s  [128,64]
    int n = id >> 6, k = id & 63; float acc = 0.f;
    for (int j = 0; j < 128; ++j) acc += We1[n*256 + j] * Wps[j*64 + k];
    fold[id] = acc;
  } else if (id < 16384) {                          // A_ds = Wd1[:, :128] @ Wphi_z  [128,64]
    int q = id - 8192; int n = q >> 6, k = q & 63; float acc = 0.f;
    for (int j = 0; j < 128; ++j) acc += Wd1[n*256 + j] * Wpz[j*64 + k];
    fold[id] = acc;
  } else if (id < 49152) {                          // G_s = Wih[:, :128] @ Wphi_s  [512,64]
    int q = id - 16384; int n = q >> 6, k = q & 63; float acc = 0.f;
    for (int j = 0; j < 128; ++j) acc += Wih[n*256 + j] * Wps[j*64 + k];
    fold[id] = acc;
  } else if (id < 81920) {                          // G_z = Wih[:, 128:] @ Wphi_z  [512,64]
    int q = id - 49152; int n = q >> 6, k = q & 63; float acc = 0.f;
    for (int j = 0; j < 128; ++j) acc += Wih[n*256 + 128 + j] * Wpz[j*64 + k];
    fold[id] = acc;
  } else if (id < 82048) {                          // b_enc1 = be1 + We1a@b_phi_s
    int n = id - 81920; float acc = be1[n];
    for (int j = 0; j < 128; ++j) acc += We1[n*256 + j] * bps[j];
    fbias[n] = acc;
  } else if (id < 82176) {                          // b_dec1 = bd1 + Wd1a@b_phi_z
    int n = id - 82048; float acc = bd1[n];
    for (int j = 0; j < 128; ++j) acc += Wd1[n*256 + j] * bpz[j];
    fbias[128 + n] = acc;
  } else if (id < 82688) {                          // b_g = bih + bhh + Wih_a@bps + Wih_b@bpz
    int n = id - 82176; float acc = bih[n] + bhh[n];
    for (int j = 0; j < 128; ++j) acc += Wih[n*256 + j]*bps[j] + Wih[n*256 + 128 + j]*bpz[j];
    fbias[256 + n] = acc;
  }
}

// ---------------- setup kernel 2: pack all layers into MFMA B-fragment order (bf16) --------
__global__ void vrnn_pack(const float* __restrict__ fold,
                          const float* __restrict__ We1, const float* __restrict__ We2,
                          const float* __restrict__ Wp1, const float* __restrict__ Wp2,
                          const float* __restrict__ Wd1, const float* __restrict__ Wd2,
                          const float* __restrict__ Whh,
                          bf16_t* __restrict__ packed) {
  int c = blockIdx.x * 256 + threadIdx.x;
  if (c >= NCHUNK) return;
  const float* src; int rs, co, Kt, base;
  if      (c < 1024)  { base = cL0;  src = fold;          rs = 64;  co = 0;   Kt = 2; }
  else if (c < 3072)  { base = cL1;  src = We1;           rs = 256; co = 128; Kt = 4; }
  else if (c < 5120)  { base = cL2;  src = We2;           rs = 128; co = 0;   Kt = 4; }
  else if (c < 7168)  { base = cL3;  src = Wp1;           rs = 128; co = 0;   Kt = 4; }
  else if (c < 9216)  { base = cL4;  src = Wp2;           rs = 128; co = 0;   Kt = 4; }
  else if (c < 10240) { base = cL5;  src = fold + 8192;   rs = 64;  co = 0;   Kt = 2; }
  else if (c < 12288) { base = cL6;  src = Wd1;           rs = 256; co = 128; Kt = 4; }
  else if (c < 13312) { base = cL7;  src = Wd2;           rs = 128; co = 0;   Kt = 4; }
  else if (c < 17408) { base = cL8;  src = fold + 16384;  rs = 64;  co = 0;   Kt = 2; }
  else if (c < 21504) { base = cL9;  src = fold + 49152;  rs = 64;  co = 0;   Kt = 2; }
  else                { base = cL10; src = Whh;           rs = 128; co = 0;   Kt = 4; }
  int local = c - base;
  int nt = local / (Kt * 64);
  int r = local - nt * Kt * 64;
  int kt = r >> 6, lane = r & 63;
  int n = nt * 16 + (lane & 15);
  int k = kt * 32 + (lane >> 4) * 8;
  const float* p = src + n * rs + co + k;
  bf16x8 v;
  #pragma unroll
  for (int j = 0; j < 8; ++j) v[j] = (bf16_t)p[j];
  *(bf16x8*)(packed + (size_t)c * 8) = v;
}

// ---------------- main persistent kernel: 64 WGs x 512 threads, 16 rows each ----------------
// 3 barriers/step:
//  P1: enc1, pri1, dec1_h, gates_{s,h}, dec2(t-1)            -> B1
//  P2: enc2 (mu/sd paired, z in-reg), pri2 (paired), recon   -> B2
//  P3: gates_z + in-reg LSTM (c in regs) -> h; dec1_z; KL    -> B3
__global__ __launch_bounds__(512, 2) void vrnn_main(
    const float* __restrict__ s, const float* __restrict__ noise,
    const bf16_t* __restrict__ packed, const float* __restrict__ fbias,
    const float* __restrict__ bp1, const float* __restrict__ bp2,
    const float* __restrict__ be2, const float* __restrict__ bd2,
    float* __restrict__ out) {
  const bf16x8* Wf = (const bf16x8*)packed;

  __shared__ __align__(16) bf16_t A_h[16 * 136];      // h (A-layout, stride 136)
  __shared__ __align__(16) bf16_t A_s[2][16 * 72];    // s_t staged, double-buffered
  __shared__ __align__(16) bf16_t A_z[16 * 72];
  __shared__ __align__(16) bf16_t A_e1[16 * 136];     // enc1 out
  __shared__ __align__(16) bf16_t A_p1[16 * 136];     // pri1 out
  __shared__ __align__(16) bf16_t A_d1[16 * 136];     // dec1 out (persists to next step)
  __shared__ float zmu_s[16 * 68], zsd_s[16 * 68];    // z stats fp32 (for KL)
  __shared__ float dec2o[16 * 68];
  __shared__ float bsm[1216];
  __shared__ float red[8];

  const int tid  = threadIdx.x;
  const int wv   = tid >> 6, ln = tid & 63;
  const int quad = ln >> 4, col = ln & 15;
  const int row0 = blockIdx.x * 16;
  const int pm_  = tid >> 5;            // pointwise row 0..15
  const int pj   = (tid & 31) * 2;      // pointwise col base (0..62)
  const int nloc0 = wv * 16 + col;      // n index for N=128 layers, tile wv
  const int j_own = wv * 16 + col;      // hidden/z index owned by this lane (gates)
  const int wq   = wv & 3;

  // biases -> LDS: [0)be1f [128)bp1 [256)be2 [384)bp2 [512)bd1f [640)bd2 [704)bg
  for (int i = tid; i < 1216; i += 512) {
    float v;
    if      (i < 128)  v = fbias[i];
    else if (i < 256)  v = bp1[i - 128];
    else if (i < 384)  v = be2[i - 256];
    else if (i < 512)  v = bp2[i - 384];
    else if (i < 640)  v = fbias[128 + (i - 512)];
    else if (i < 704)  v = bd2[i - 640];
    else               v = fbias[256 + (i - 704)];
    bsm[i] = v;
  }
  for (int i = tid; i < 16 * 136; i += 512) A_h[i] = (bf16_t)0.0f;
  { // stage s_0
    float2 v = *(const float2*)(s + (0 * BB + row0 + pm_) * 64 + pj);
    A_s[0][pm_ * 72 + pj]     = (bf16_t)v.x;
    A_s[0][pm_ * 72 + pj + 1] = (bf16_t)v.y;
  }

  // ---- register-resident weights ----
  // gates: z-part + h-part (critical path), 24 frags
  bf16x8 rb9[4][2], rb10[4][4];
  #pragma unroll
  for (int i = 0; i < 4; ++i) {
    int nt = wv + 8 * i;
    rb9[i][0] = Wf[cL9 + (nt * 2 + 0) * 64 + ln];
    rb9[i][1] = Wf[cL9 + (nt * 2 + 1) * 64 + ln];
    #pragma unroll
    for (int k = 0; k < 4; ++k) rb10[i][k] = Wf[cL10 + (nt * 4 + k) * 64 + ln];
  }
  // enc1 (6 frags)
  bf16x8 wE0[2], wE1[4];
  wE0[0] = Wf[cL0 + (wv * 2 + 0) * 64 + ln];
  wE0[1] = Wf[cL0 + (wv * 2 + 1) * 64 + ln];
  #pragma unroll
  for (int k = 0; k < 4; ++k) wE1[k] = Wf[cL1 + (wv * 4 + k) * 64 + ln];
  // enc2 (waves 0-3) / pri2 (waves 4-7), mu/sd paired: 8 frags
  bf16x8 wmu[4], wsd[4];
  {
    int base2 = (wv < 4) ? cL2 : cL4;
    #pragma unroll
    for (int k = 0; k < 4; ++k) {
      wmu[k] = Wf[base2 + (wq * 4 + k) * 64 + ln];
      wsd[k] = Wf[base2 + ((wq + 4) * 4 + k) * 64 + ln];
    }
  }

  f32x4 c_reg = {0.f, 0.f, 0.f, 0.f};   // LSTM cell state, rows quad*4+r, col j_own
  float kl_acc = 0.0f, rc_acc = 0.0f;
  __syncthreads();

  for (int t = 0; t < TT; ++t) {
    const int sb = t & 1;
    // ---- step-top global prefetches (drained at first USE, not at barriers) ----
    float nzr[4];
    if (wv < 4) {
      #pragma unroll
      for (int r = 0; r < 4; ++r)
        nzr[r] = noise[(t * BB + row0 + quad * 4 + r) * 64 + j_own];
    }
    float2 svv = make_float2(0.f, 0.f);
    if (t + 1 < TT) svv = *(const float2*)(s + ((t + 1) * BB + row0 + pm_) * 64 + pj);
    float2 spv = make_float2(0.f, 0.f);
    if (t > 0) spv = *(const float2*)(s + ((t - 1) * BB + row0 + pm_) * 64 + pj);

    // ---- streamed weights for this step (L2-resident, off critical chain) ----
    bf16x8 w8[4][2], wP1[4], wD1[4];
    #pragma unroll
    for (int i = 0; i < 4; ++i) {
      int nt = wv + 8 * i;
      w8[i][0] = Wf[cL8 + (nt * 2 + 0) * 64 + ln];
      w8[i][1] = Wf[cL8 + (nt * 2 + 1) * 64 + ln];
    }
    #pragma unroll
    for (int k = 0; k < 4; ++k) {
      wP1[k] = Wf[cL3 + (wv * 4 + k) * 64 + ln];
      wD1[k] = Wf[cL6 + (wv * 4 + k) * 64 + ln];
    }

    // ================= phase 1 =================
    bf16x8 ah0 = *(const bf16x8*)&A_h[col * 136 + 0 + quad * 8];
    bf16x8 ah1 = *(const bf16x8*)&A_h[col * 136 + 32 + quad * 8];
    bf16x8 ah2 = *(const bf16x8*)&A_h[col * 136 + 64 + quad * 8];
    bf16x8 ah3 = *(const bf16x8*)&A_h[col * 136 + 96 + quad * 8];
    bf16x8 as0 = *(const bf16x8*)&A_s[sb][col * 72 + 0 + quad * 8];
    bf16x8 as1 = *(const bf16x8*)&A_s[sb][col * 72 + 32 + quad * 8];

    {  // enc1 (critical chain head) -> A_e1
      float bv = bsm[nloc0];
      f32x4 c = {bv, bv, bv, bv};
      c = mfma16(as0, wE0[0], c);
      c = mfma16(as1, wE0[1], c);
      c = mfma16(ah0, wE1[0], c);
      c = mfma16(ah1, wE1[1], c);
      c = mfma16(ah2, wE1[2], c);
      c = mfma16(ah3, wE1[3], c);
      #pragma unroll
      for (int r = 0; r < 4; ++r)
        A_e1[(quad * 4 + r) * 136 + nloc0] = (bf16_t)fmaxf(c[r], 0.0f);
    }
    f32x4 Cg[4];
    #pragma unroll
    for (int i = 0; i < 4; ++i) {  // gates partial: h (resident) + s (streamed)
      float bv = bsm[704 + j_own + 128 * i];
      f32x4 cc = {bv, bv, bv, bv};
      cc = mfma16(ah0, rb10[i][0], cc);
      cc = mfma16(ah1, rb10[i][1], cc);
      cc = mfma16(ah2, rb10[i][2], cc);
      cc = mfma16(ah3, rb10[i][3], cc);
      cc = mfma16(as0, w8[i][0], cc);
      cc = mfma16(as1, w8[i][1], cc);
      Cg[i] = cc;
    }
    {  // pri1 -> A_p1
      float bv = bsm[128 + nloc0];
      f32x4 c = {bv, bv, bv, bv};
      c = mfma16(ah0, wP1[0], c);
      c = mfma16(ah1, wP1[1], c);
      c = mfma16(ah2, wP1[2], c);
      c = mfma16(ah3, wP1[3], c);
      #pragma unroll
      for (int r = 0; r < 4; ++r)
        A_p1[(quad * 4 + r) * 136 + nloc0] = (bf16_t)fmaxf(c[r], 0.0f);
    }
    f32x4 Cd;  // dec1 h-part, held to phase 3
    {
      float bv = bsm[512 + nloc0];
      f32x4 c = {bv, bv, bv, bv};
      c = mfma16(ah0, wD1[0], c);
      c = mfma16(ah1, wD1[1], c);
      c = mfma16(ah2, wD1[2], c);
      c = mfma16(ah3, wD1[3], c);
      Cd = c;
    }
    if (wv >= 4 && t > 0) {  // dec2 for step t-1 on A_d1
      bf16x8 ad0 = *(const bf16x8*)&A_d1[col * 136 + 0 + quad * 8];
      bf16x8 ad1 = *(const bf16x8*)&A_d1[col * 136 + 32 + quad * 8];
      bf16x8 ad2 = *(const bf16x8*)&A_d1[col * 136 + 64 + quad * 8];
      bf16x8 ad3 = *(const bf16x8*)&A_d1[col * 136 + 96 + quad * 8];
      bf16x8 w7[4];
      #pragma unroll
      for (int k = 0; k < 4; ++k) w7[k] = Wf[cL7 + (wq * 4 + k) * 64 + ln];
      float bv = bsm[640 + wq * 16 + col];
      f32x4 c = {bv, bv, bv, bv};
      c = mfma16(ad0, w7[0], c);
      c = mfma16(ad1, w7[1], c);
      c = mfma16(ad2, w7[2], c);
      c = mfma16(ad3, w7[3], c);
      #pragma unroll
      for (int r = 0; r < 4; ++r)
        dec2o[(quad * 4 + r) * 68 + wq * 16 + col] = c[r];
    }
    wg_barrier();  // B1

    // ================= phase 2 =================
    float Pmu[4], Pps[4];  // pri2 stats (waves 4-7), live into phase 3
    if (wv < 4) {          // enc2 paired -> z in-register -> A_z + zstat
      bf16x8 ae0 = *(const bf16x8*)&A_e1[col * 136 + 0 + quad * 8];
      bf16x8 ae1 = *(const bf16x8*)&A_e1[col * 136 + 32 + quad * 8];
      bf16x8 ae2 = *(const bf16x8*)&A_e1[col * 136 + 64 + quad * 8];
      bf16x8 ae3 = *(const bf16x8*)&A_e1[col * 136 + 96 + quad * 8];
      float bm = bsm[256 + wq * 16 + col], bs = bsm[256 + 64 + wq * 16 + col];
      f32x4 cm = {bm, bm, bm, bm};
      f32x4 cs = {bs, bs, bs, bs};
      cm = mfma16(ae0, wmu[0], cm); cs = mfma16(ae0, wsd[0], cs);
      cm = mfma16(ae1, wmu[1], cm); cs = mfma16(ae1, wsd[1], cs);
      cm = mfma16(ae2, wmu[2], cm); cs = mfma16(ae2, wsd[2], cs);
      cm = mfma16(ae3, wmu[3], cm); cs = mfma16(ae3, wsd[3], cs);
      #pragma unroll
      for (int r = 0; r < 4; ++r) {
        float zm = cm[r];
        float zs = softplus_f(cs[r]);
        float z = zm + zs * nzr[r];
        int m = quad * 4 + r;
        A_z[m * 72 + j_own] = (bf16_t)z;
        zmu_s[m * 68 + j_own] = zm;
        zsd_s[m * 68 + j_own] = zs;
      }
    } else {               // pri2 paired, stats stay in registers
      bf16x8 ap0 = *(const bf16x8*)&A_p1[col * 136 + 0 + quad * 8];
      bf16x8 ap1 = *(const bf16x8*)&A_p1[col * 136 + 32 + quad * 8];
      bf16x8 ap2 = *(const bf16x8*)&A_p1[col * 136 + 64 + quad * 8];
      bf16x8 ap3 = *(const bf16x8*)&A_p1[col * 136 + 96 + quad * 8];
      float bm = bsm[384 + wq * 16 + col], bs = bsm[384 + 64 + wq * 16 + col];
      f32x4 cm = {bm, bm, bm, bm};
      f32x4 cs = {bs, bs, bs, bs};
      cm = mfma16(ap0, wmu[0], cm); cs = mfma16(ap0, wsd[0], cs);
      cm = mfma16(ap1, wmu[1], cm); cs = mfma16(ap1, wsd[1], cs);
      cm = mfma16(ap2, wmu[2], cm); cs = mfma16(ap2, wsd[2], cs);
      cm = mfma16(ap3, wmu[3], cm); cs = mfma16(ap3, wsd[3], cs);
      #pragma unroll
      for (int r = 0; r < 4; ++r) { Pmu[r] = cm[r]; Pps[r] = softplus_f(cs[r]); }
    }
    if (t > 0) {  // recon for t-1
      float d0 = dec2o[pm_ * 68 + pj] - spv.x;
      float d1 = dec2o[pm_ * 68 + pj + 1] - spv.y;
      rc_acc += 0.5f * (d0 * d0 + d1 * d1);
    }
    if (t + 1 < TT) {  // stage s_{t+1}
      A_s[sb ^ 1][pm_ * 72 + pj]     = (bf16_t)svv.x;
      A_s[sb ^ 1][pm_ * 72 + pj + 1] = (bf16_t)svv.y;
    }
    wg_barrier();  // B2

    // ================= phase 3 =================
    bf16x8 az0 = *(const bf16x8*)&A_z[col * 72 + 0 + quad * 8];
    bf16x8 az1 = *(const bf16x8*)&A_z[col * 72 + 32 + quad * 8];
    #pragma unroll
    for (int i = 0; i < 4; ++i) {
      Cg[i] = mfma16(az0, rb9[i][0], Cg[i]);
      Cg[i] = mfma16(az1, rb9[i][1], Cg[i]);
    }
    {  // dec1 z-part, relu, -> A_d1 (consumed next step)
      bf16x8 w5a = Wf[cL5 + (wv * 2 + 0) * 64 + ln];
      bf16x8 w5b = Wf[cL5 + (wv * 2 + 1) * 64 + ln];
      Cd = mfma16(az0, w5a, Cd);
      Cd = mfma16(az1, w5b, Cd);
      #pragma unroll
      for (int r = 0; r < 4; ++r)
        A_d1[(quad * 4 + r) * 136 + nloc0] = (bf16_t)fmaxf(Cd[r], 0.0f);
    }
    // in-register LSTM update: lane owns rows m=quad*4+r, hidden j_own
    #pragma unroll
    for (int r = 0; r < 4; ++r) {
      float gi = sigm(Cg[0][r]);
      float gf = sigm(Cg[1][r]);
      float gg = tanh_f(Cg[2][r]);
      float go = sigm(Cg[3][r]);
      float cn = gf * c_reg[r] + gi * gg;
      c_reg[r] = cn;
      A_h[(quad * 4 + r) * 136 + j_own] = (bf16_t)(go * tanh_f(cn));
    }
    if (wv >= 4) {  // KL: z stats from LDS, pri stats in registers
      #pragma unroll
      for (int r = 0; r < 4; ++r) {
        int m = quad * 4 + r;
        float zm = zmu_s[m * 68 + wq * 16 + col];
        float zs = zsd_s[m * 68 + wq * 16 + col];
        float dm = zm - Pmu[r];
        float ps = Pps[r];
        float den = __expf(2.0f * ps) - 1.0f;
        kl_acc += 0.5f * (2.0f * __logf(ps + 0.01f) - 2.0f * __logf(zs + 0.01f)
                          + (zs * zs + dm * dm) / den);
      }
    }
    wg_barrier();  // B3 (h, A_d1 published)
  }

  // epilogue: dec2 + recon for t = TT-1
  if (wv >= 4) {
    bf16x8 ad0 = *(const bf16x8*)&A_d1[col * 136 + 0 + quad * 8];
    bf16x8 ad1 = *(const bf16x8*)&A_d1[col * 136 + 32 + quad * 8];
    bf16x8 ad2 = *(const bf16x8*)&A_d1[col * 136 + 64 + quad * 8];
    bf16x8 ad3 = *(const bf16x8*)&A_d1[col * 136 + 96 + quad * 8];
    bf16x8 w7[4];
    #pragma unroll
    for (int k = 0; k < 4; ++k) w7[k] = Wf[cL7 + (wq * 4 + k) * 64 + ln];
    float bv = bsm[640 + wq * 16 + col];
    f32x4 c = {bv, bv, bv, bv};
    c = mfma16(ad0, w7[0], c);
    c = mfma16(ad1, w7[1], c);
    c = mfma16(ad2, w7[2], c);
    c = mfma16(ad3, w7[3], c);
    #pragma unroll
    for (int r = 0; r < 4; ++r)
      dec2o[(quad * 4 + r) * 68 + wq * 16 + col] = c[r];
  }
  __syncthreads();
  {
    float2 sl = *(const float2*)(s + ((TT - 1) * BB + row0 + pm_) * 64 + pj);
    float d0 = dec2o[pm_ * 68 + pj] - sl.x;
    float d1 = dec2o[pm_ * 68 + pj + 1] - sl.y;
    rc_acc += 0.5f * (d0 * d0 + d1 * d1);
  }

  float tot = (kl_acc + rc_acc) * (1.0f / 1024.0f);
  #pragma unroll
  for (int off = 32; off > 0; off >>= 1) tot += __shfl_down(tot, off);
  if (ln == 0) red[wv] = tot;
  __syncthreads();
  if (tid == 0) {
    float sum = 0.f;
    #pragma unroll
    for (int i = 0; i < 8; ++i) sum += red[i];
    atomicAdd(out, sum);
  }
}

extern "C" void kernel_launch(void* const* d_in, const int* in_sizes, int n_in,
                              void* d_out, int out_size, void* d_ws, size_t ws_size,
                              hipStream_t stream) {
  (void)in_sizes; (void)n_in; (void)out_size; (void)ws_size;
  const float* s   = (const float*)d_in[0];
  const float* nz  = (const float*)d_in[1];
  const float* Wps = (const float*)d_in[2];
  const float* bps = (const float*)d_in[3];
  const float* Wpz = (const float*)d_in[4];
  const float* bpz = (const float*)d_in[5];
  const float* Wp1 = (const float*)d_in[6];
  const float* bp1 = (const float*)d_in[7];
  const float* Wp2 = (const float*)d_in[8];
  const float* bp2 = (const float*)d_in[9];
  const float* We1 = (const float*)d_in[10];
  const float* be1 = (const float*)d_in[11];
  const float* We2 = (const float*)d_in[12];
  const float* be2 = (const float*)d_in[13];
  const float* Wih = (const float*)d_in[14];
  const float* bih = (const float*)d_in[15];
  const float* Whh = (const float*)d_in[16];
  const float* bhh = (const float*)d_in[17];
  const float* Wd1 = (const float*)d_in[18];
  const float* bd1 = (const float*)d_in[19];
  const float* Wd2 = (const float*)d_in[20];
  const float* bd2 = (const float*)d_in[21];

  bf16_t* packed = (bf16_t*)d_ws;
  float* fbias = (float*)((char*)d_ws + WS_FBIAS_OFF);
  float* fold  = (float*)((char*)d_ws + WS_FOLD_OFF);

  hipMemsetAsync(d_out, 0, sizeof(float), stream);
  vrnn_fold<<<(82688 + 255) / 256, 256, 0, stream>>>(We1, Wd1, Wih, Wps, Wpz, bps, bpz,
                                                     be1, bd1, bih, bhh, fold, fbias);
  vrnn_pack<<<(NCHUNK + 255) / 256, 256, 0, stream>>>(fold, We1, We2, Wp1, Wp2, Wd1, Wd2,
                                                      Whh, packed);
  vrnn_main<<<64, 512, 0, stream>>>(s, nz, packed, fbias, bp1, bp2, be2, bd2, (float*)d_out);
}

// Round 3
// 2188.162 us; speedup vs baseline: 2.1934x; 2.1934x over previous
//
#include <hip/hip_runtime.h>

typedef __bf16 bf16_t;
typedef bf16_t bf16x8 __attribute__((ext_vector_type(8)));
typedef float  f32x4  __attribute__((ext_vector_type(4)));

#define TT 512
#define BB 1024

// packed weight chunk bases (16B chunks). Layer k: [N,K] row-major source.
#define cL0   0      // enc1_s  N=128 K=64   (folded We1a*Wphi_s)
#define cL1   1024   // enc1_h  N=128 K=128  (We1[:,128:])
#define cL2   3072   // enc2    N=128 K=128
#define cL3   5120   // pri1    N=128 K=128
#define cL4   7168   // pri2    N=128 K=128
#define cL5   9216   // dec1_z  N=128 K=64   (folded Wd1a*Wphi_z)
#define cL6   10240  // dec1_h  N=128 K=128  (Wd1[:,128:])
#define cL7   12288  // dec2    N=64  K=128
#define cL8   13312  // gates_s N=512 K=64   (folded Wih_a*Wphi_s)
#define cL9   17408  // gates_z N=512 K=64   (folded Wih_b*Wphi_z)
#define cL10  21504  // gates_h N=512 K=128  (W_hh)
#define NCHUNK 29696

#define WS_FBIAS_OFF 475136            // 768 floats (b_enc1f[128], b_dec1f[128], b_g[512])
#define WS_FOLD_OFF  478208            // 81920 floats
#define WS_HSEQ_OFF  1048576           // bf16 h sequence: 512 slots x 1024 x 128
#define WS_NEED (WS_HSEQ_OFF + (size_t)TT * BB * 128 * 2)

__device__ __forceinline__ f32x4 mfma16(bf16x8 a, bf16x8 b, f32x4 c) {
  return __builtin_amdgcn_mfma_f32_16x16x32_bf16(a, b, c, 0, 0, 0);
}
__device__ __forceinline__ float sigm(float x) { return 1.0f / (1.0f + __expf(-x)); }
__device__ __forceinline__ float tanh_f(float x) {
  x = fminf(fmaxf(x, -15.0f), 15.0f);
  float e = __expf(2.0f * x);
  return (e - 1.0f) / (e + 1.0f);
}
__device__ __forceinline__ float softplus_f(float x) {
  return (x > 15.0f) ? x : __logf(1.0f + __expf(x));
}
// LDS-only barrier: no vmcnt drain (global loads wait at their use).
__device__ __forceinline__ void wg_barrier() {
  asm volatile("s_waitcnt lgkmcnt(0)\n\ts_barrier" ::: "memory");
}
// Pin a loaded fragment as an opaque asm result: cannot be rematerialized
// by reloading memory -> forced to stay register-resident (or spill, which
// the register budget is sized to avoid).
__device__ __forceinline__ void keep(bf16x8& v) { asm volatile("" : "+v"(v)); }

// ---------------- setup kernel 1: fold phi layers into downstream weights ----------------
__global__ void vrnn_fold(const float* __restrict__ We1, const float* __restrict__ Wd1,
                          const float* __restrict__ Wih,
                          const float* __restrict__ Wps, const float* __restrict__ Wpz,
                          const float* __restrict__ bps, const float* __restrict__ bpz,
                          const float* __restrict__ be1, const float* __restrict__ bd1,
                          const float* __restrict__ bih, const float* __restrict__ bhh,
                          float* __restrict__ fold, float* __restrict__ fbias) {
  int id = blockIdx.x * 256 + threadIdx.x;
  if (id < 8192) {                                  // A_es = We1[:, :128] @ Wphi_s  [128,64]
    int n = id >> 6, k = id & 63; float acc = 0.f;
    for (int j = 0; j < 128; ++j) acc += We1[n*256 + j] * Wps[j*64 + k];
    fold[id] = acc;
  } else if (id < 16384) {                          // A_ds = Wd1[:, :128] @ Wphi_z  [128,64]
    int q = id - 8192; int n = q >> 6, k = q & 63; float acc = 0.f;
    for (int j = 0; j < 128; ++j) acc += Wd1[n*256 + j] * Wpz[j*64 + k];
    fold[id] = acc;
  } else if (id < 49152) {                          // G_s = Wih[:, :128] @ Wphi_s  [512,64]
    int q = id - 16384; int n = q >> 6, k = q & 63; float acc = 0.f;
    for (int j = 0; j < 128; ++j) acc += Wih[n*256 + j] * Wps[j*64 + k];
    fold[id] = acc;
  } else if (id < 81920) {                          // G_z = Wih[:, 128:] @ Wphi_z  [512,64]
    int q = id - 49152; int n = q >> 6, k = q & 63; float acc = 0.f;
    for (int j = 0; j < 128; ++j) acc += Wih[n*256 + 128 + j] * Wpz[j*64 + k];
    fold[id] = acc;
  } else if (id < 82048) {                          // b_enc1f = be1 + We1a@b_phi_s
    int n = id - 81920; float acc = be1[n];
    for (int j = 0; j < 128; ++j) acc += We1[n*256 + j] * bps[j];
    fbias[n] = acc;
  } else if (id < 82176) {                          // b_dec1f = bd1 + Wd1a@b_phi_z
    int n = id - 82048; float acc = bd1[n];
    for (int j = 0; j < 128; ++j) acc += Wd1[n*256 + j] * bpz[j];
    fbias[128 + n] = acc;
  } else if (id < 82688) {                          // b_g = bih + bhh + Wih_a@bps + Wih_b@bpz
    int n = id - 82176; float acc = bih[n] + bhh[n];
    for (int j = 0; j < 128; ++j) acc += Wih[n*256 + j]*bps[j] + Wih[n*256 + 128 + j]*bpz[j];
    fbias[256 + n] = acc;
  }
}

// ---------------- setup kernel 2: pack all layers into MFMA B-fragment order -------------
__global__ void vrnn_pack(const float* __restrict__ fold,
                          const float* __restrict__ We1, const float* __restrict__ We2,
                          const float* __restrict__ Wp1, const float* __restrict__ Wp2,
                          const float* __restrict__ Wd1, const float* __restrict__ Wd2,
                          const float* __restrict__ Whh,
                          bf16_t* __restrict__ packed) {
  int c = blockIdx.x * 256 + threadIdx.x;
  if (c >= NCHUNK) return;
  const float* src; int rs, co, Kt, base;
  if      (c < 1024)  { base = cL0;  src = fold;          rs = 64;  co = 0;   Kt = 2; }
  else if (c < 3072)  { base = cL1;  src = We1;           rs = 256; co = 128; Kt = 4; }
  else if (c < 5120)  { base = cL2;  src = We2;           rs = 128; co = 0;   Kt = 4; }
  else if (c < 7168)  { base = cL3;  src = Wp1;           rs = 128; co = 0;   Kt = 4; }
  else if (c < 9216)  { base = cL4;  src = Wp2;           rs = 128; co = 0;   Kt = 4; }
  else if (c < 10240) { base = cL5;  src = fold + 8192;   rs = 64;  co = 0;   Kt = 2; }
  else if (c < 12288) { base = cL6;  src = Wd1;           rs = 256; co = 128; Kt = 4; }
  else if (c < 13312) { base = cL7;  src = Wd2;           rs = 128; co = 0;   Kt = 4; }
  else if (c < 17408) { base = cL8;  src = fold + 16384;  rs = 64;  co = 0;   Kt = 2; }
  else if (c < 21504) { base = cL9;  src = fold + 49152;  rs = 64;  co = 0;   Kt = 2; }
  else                { base = cL10; src = Whh;           rs = 128; co = 0;   Kt = 4; }
  int local = c - base;
  int nt = local / (Kt * 64);
  int r = local - nt * Kt * 64;
  int kt = r >> 6, lane = r & 63;
  int n = nt * 16 + (lane & 15);
  int k = kt * 32 + (lane >> 4) * 8;
  const float* p = src + n * rs + co + k;
  bf16x8 v;
  #pragma unroll
  for (int j = 0; j < 8; ++j) v[j] = (bf16_t)p[j];
  *(bf16x8*)(packed + (size_t)c * 8) = v;
}

// ---------------- recurrence loop kernel: 64 WGs x 512 thr, 16 rows each -----------------
// Minimal serial work: enc1 -> enc2/z -> gates -> LSTM. Stores h[t] to hseq.
__global__ __launch_bounds__(512, 2) void vrnn_loop(
    const float* __restrict__ s, const float* __restrict__ noise,
    const bf16_t* __restrict__ packed, const float* __restrict__ fbias,
    const float* __restrict__ be2, bf16_t* __restrict__ hseq) {
  const bf16x8* Wf = (const bf16x8*)packed;

  __shared__ __align__(16) bf16_t A_h[2][16 * 136];
  __shared__ __align__(16) bf16_t A_s[2][16 * 72];
  __shared__ __align__(16) bf16_t A_z[16 * 72];
  __shared__ __align__(16) bf16_t A_e1[16 * 136];
  __shared__ float bsm[768];   // [0)b_enc1f [128)be2 [256)b_g

  const int tid  = threadIdx.x;
  const int wv   = tid >> 6, ln = tid & 63;
  const int quad = ln >> 4, col = ln & 15;
  const int row0 = blockIdx.x * 16;
  const int pm_  = tid >> 5;
  const int pj   = (tid & 31) * 2;
  const int nloc0 = wv * 16 + col;
  const int j_own = wv * 16 + col;
  const int wq   = wv & 3;

  for (int i = tid; i < 768; i += 512) {
    float v;
    if      (i < 128) v = fbias[i];
    else if (i < 256) v = be2[i - 128];
    else              v = fbias[256 + (i - 256)];
    bsm[i] = v;
  }
  for (int i = tid; i < 16 * 136; i += 512) A_h[0][i] = (bf16_t)0.0f;
  { // stage s_0
    float2 v = *(const float2*)(s + ((size_t)0 * BB + row0 + pm_) * 64 + pj);
    A_s[0][pm_ * 72 + pj]     = (bf16_t)v.x;
    A_s[0][pm_ * 72 + pj + 1] = (bf16_t)v.y;
  }
  { // zero hseq slot 0 (h_{-1}) for this WG's rows
    unsigned long long* p = (unsigned long long*)(hseq + (size_t)row0 * 128);
    p[tid] = 0ull;  // 512 threads x 8B = 4KB = 2048 bf16
  }

  // resident: gates h-part only (16 frags = 64 VGPRs), pinned.
  bf16x8 rb10[4][4];
  #pragma unroll
  for (int i = 0; i < 4; ++i) {
    int nt = wv + 8 * i;
    #pragma unroll
    for (int k = 0; k < 4; ++k) { rb10[i][k] = Wf[cL10 + (nt * 4 + k) * 64 + ln]; keep(rb10[i][k]); }
  }
  // initial prefetch for t=0 phase 1 (enc1 + gates_s)
  bf16x8 wE[6], rb8[4][2];
  wE[0] = Wf[cL0 + (wv * 2 + 0) * 64 + ln];
  wE[1] = Wf[cL0 + (wv * 2 + 1) * 64 + ln];
  #pragma unroll
  for (int k = 0; k < 4; ++k) wE[2 + k] = Wf[cL1 + (wv * 4 + k) * 64 + ln];
  #pragma unroll
  for (int i = 0; i < 4; ++i) {
    int nt = wv + 8 * i;
    rb8[i][0] = Wf[cL8 + (nt * 2 + 0) * 64 + ln];
    rb8[i][1] = Wf[cL8 + (nt * 2 + 1) * 64 + ln];
  }

  f32x4 c_reg = {0.f, 0.f, 0.f, 0.f};
  __syncthreads();

  int cb = 0;
  for (int t = 0; t < TT; ++t) {
    const int sb = t & 1;
    // laundered pointer: per-iteration opaque offset blocks LICM of streamed
    // weight loads (keeps them as in-loop prefetches at the points below).
    int zo = 0;
    asm volatile("" : "+s"(zo));
    const bf16x8* Wfv = Wf + zo;

    // ---- P1-top issues: enc2 weights (used P2), noise, s_{t+1} ----
    bf16x8 wmu[4], wsd[4];
    float nzr[4];
    if (wv < 4) {
      #pragma unroll
      for (int k = 0; k < 4; ++k) {
        wmu[k] = Wfv[cL2 + (wq * 4 + k) * 64 + ln];
        wsd[k] = Wfv[cL2 + ((wq + 4) * 4 + k) * 64 + ln];
      }
      #pragma unroll
      for (int r = 0; r < 4; ++r)
        nzr[r] = noise[((size_t)t * BB + row0 + quad * 4 + r) * 64 + j_own];
    }
    float2 svv = make_float2(0.f, 0.f);
    if (t + 1 < TT) svv = *(const float2*)(s + ((size_t)(t + 1) * BB + row0 + pm_) * 64 + pj);

    // ---- P1: enc1 + gates s/h partial ----
    bf16x8 ah0 = *(const bf16x8*)&A_h[cb][col * 136 + 0 + quad * 8];
    bf16x8 ah1 = *(const bf16x8*)&A_h[cb][col * 136 + 32 + quad * 8];
    bf16x8 ah2 = *(const bf16x8*)&A_h[cb][col * 136 + 64 + quad * 8];
    bf16x8 ah3 = *(const bf16x8*)&A_h[cb][col * 136 + 96 + quad * 8];
    bf16x8 as0 = *(const bf16x8*)&A_s[sb][col * 72 + 0 + quad * 8];
    bf16x8 as1 = *(const bf16x8*)&A_s[sb][col * 72 + 32 + quad * 8];

    {  // enc1 -> A_e1
      float bv = bsm[nloc0];
      f32x4 c = {bv, bv, bv, bv};
      c = mfma16(as0, wE[0], c);
      c = mfma16(as1, wE[1], c);
      c = mfma16(ah0, wE[2], c);
      c = mfma16(ah1, wE[3], c);
      c = mfma16(ah2, wE[4], c);
      c = mfma16(ah3, wE[5], c);
      #pragma unroll
      for (int r = 0; r < 4; ++r)
        A_e1[(quad * 4 + r) * 136 + nloc0] = (bf16_t)fmaxf(c[r], 0.0f);
    }
    f32x4 Cg[4];
    #pragma unroll
    for (int i = 0; i < 4; ++i) {
      float bv = bsm[256 + j_own + 128 * i];
      f32x4 cc = {bv, bv, bv, bv};
      cc = mfma16(ah0, rb10[i][0], cc);
      cc = mfma16(ah1, rb10[i][1], cc);
      cc = mfma16(ah2, rb10[i][2], cc);
      cc = mfma16(ah3, rb10[i][3], cc);
      cc = mfma16(as0, rb8[i][0], cc);
      cc = mfma16(as1, rb8[i][1], cc);
      Cg[i] = cc;
    }
    wg_barrier();  // B1

    // ---- P2-top issue: gates-z weights (used P3) ----
    bf16x8 rb9[4][2];
    #pragma unroll
    for (int i = 0; i < 4; ++i) {
      int nt = wv + 8 * i;
      rb9[i][0] = Wfv[cL9 + (nt * 2 + 0) * 64 + ln];
      rb9[i][1] = Wfv[cL9 + (nt * 2 + 1) * 64 + ln];
    }
    // ---- P2: enc2 (waves 0-3) -> z; stage s_{t+1} ----
    if (wv < 4) {
      bf16x8 ae0 = *(const bf16x8*)&A_e1[col * 136 + 0 + quad * 8];
      bf16x8 ae1 = *(const bf16x8*)&A_e1[col * 136 + 32 + quad * 8];
      bf16x8 ae2 = *(const bf16x8*)&A_e1[col * 136 + 64 + quad * 8];
      bf16x8 ae3 = *(const bf16x8*)&A_e1[col * 136 + 96 + quad * 8];
      float bm = bsm[128 + wq * 16 + col], bs = bsm[128 + 64 + wq * 16 + col];
      f32x4 cm = {bm, bm, bm, bm};
      f32x4 cs = {bs, bs, bs, bs};
      cm = mfma16(ae0, wmu[0], cm); cs = mfma16(ae0, wsd[0], cs);
      cm = mfma16(ae1, wmu[1], cm); cs = mfma16(ae1, wsd[1], cs);
      cm = mfma16(ae2, wmu[2], cm); cs = mfma16(ae2, wsd[2], cs);
      cm = mfma16(ae3, wmu[3], cm); cs = mfma16(ae3, wsd[3], cs);
      #pragma unroll
      for (int r = 0; r < 4; ++r) {
        float z = cm[r] + softplus_f(cs[r]) * nzr[r];
        A_z[(quad * 4 + r) * 72 + wq * 16 + col] = (bf16_t)z;
      }
    }
    if (t + 1 < TT) {
      A_s[sb ^ 1][pm_ * 72 + pj]     = (bf16_t)svv.x;
      A_s[sb ^ 1][pm_ * 72 + pj + 1] = (bf16_t)svv.y;
    }
    wg_barrier();  // B2

    // ---- P3-top issues: next step's enc1 + gates-s weights ----
    wE[0] = Wfv[cL0 + (wv * 2 + 0) * 64 + ln];
    wE[1] = Wfv[cL0 + (wv * 2 + 1) * 64 + ln];
    #pragma unroll
    for (int k = 0; k < 4; ++k) wE[2 + k] = Wfv[cL1 + (wv * 4 + k) * 64 + ln];
    #pragma unroll
    for (int i = 0; i < 4; ++i) {
      int nt = wv + 8 * i;
      rb8[i][0] = Wfv[cL8 + (nt * 2 + 0) * 64 + ln];
      rb8[i][1] = Wfv[cL8 + (nt * 2 + 1) * 64 + ln];
    }
    // ---- P3: gates z-part + LSTM; publish h ----
    {
      bf16x8 az0 = *(const bf16x8*)&A_z[col * 72 + 0 + quad * 8];
      bf16x8 az1 = *(const bf16x8*)&A_z[col * 72 + 32 + quad * 8];
      #pragma unroll
      for (int i = 0; i < 4; ++i) {
        Cg[i] = mfma16(az0, rb9[i][0], Cg[i]);
        Cg[i] = mfma16(az1, rb9[i][1], Cg[i]);
      }
    }
    bf16_t* hp = hseq + (size_t)(t + 1) * BB * 128;
    #pragma unroll
    for (int r = 0; r < 4; ++r) {
      float gi = sigm(Cg[0][r]);
      float gf = sigm(Cg[1][r]);
      float gg = tanh_f(Cg[2][r]);
      float go = sigm(Cg[3][r]);
      float cn = gf * c_reg[r] + gi * gg;
      c_reg[r] = cn;
      bf16_t hv = (bf16_t)(go * tanh_f(cn));
      A_h[cb ^ 1][(quad * 4 + r) * 136 + j_own] = hv;
      if (t + 1 < TT) hp[(size_t)(row0 + quad * 4 + r) * 128 + j_own] = hv;
    }
    wg_barrier();  // B3
    cb ^= 1;
  }
}

// ---------------- tail kernel: prior/decoder/KL/recon over all (t, rows) -----------------
__global__ __launch_bounds__(512, 2) void vrnn_tail(
    const float* __restrict__ s, const float* __restrict__ noise,
    const bf16_t* __restrict__ packed, const float* __restrict__ fbias,
    const float* __restrict__ bp1, const float* __restrict__ bp2,
    const float* __restrict__ be2, const float* __restrict__ bd2,
    const bf16_t* __restrict__ hseq, float* __restrict__ out) {
  const bf16x8* Wf = (const bf16x8*)packed;

  __shared__ __align__(16) bf16_t A_h[16 * 136];
  __shared__ __align__(16) bf16_t A_s[16 * 72];
  __shared__ __align__(16) bf16_t A_z[16 * 72];
  __shared__ __align__(16) bf16_t A_e1[16 * 136];
  __shared__ __align__(16) bf16_t A_p1[16 * 136];
  __shared__ __align__(16) bf16_t A_d1[16 * 136];
  __shared__ float zmu_s[16 * 68], zsd_s[16 * 68];
  __shared__ float dec2o[16 * 68];
  __shared__ float bsm[704];  // [0)be1f [128)bp1 [256)be2 [384)bp2 [512)bd1f [640)bd2
  __shared__ float red[8];

  const int tid  = threadIdx.x;
  const int wv   = tid >> 6, ln = tid & 63;
  const int quad = ln >> 4, col = ln & 15;
  const int pm_  = tid >> 5;
  const int pj   = (tid & 31) * 2;
  const int nloc0 = wv * 16 + col;
  const int wq   = wv & 3;

  for (int i = tid; i < 704; i += 512) {
    float v;
    if      (i < 128) v = fbias[i];
    else if (i < 256) v = bp1[i - 128];
    else if (i < 384) v = be2[i - 256];
    else if (i < 512) v = bp2[i - 384];
    else if (i < 640) v = fbias[128 + (i - 512)];
    else              v = bd2[i - 640];
    bsm[i] = v;
  }

  // resident weights (~112 VGPRs), pinned.
  bf16x8 wE[6], wP1[4], wmu[4], wsd[4], wD1[4], w5[2], w7[4];
  wE[0] = Wf[cL0 + (wv * 2 + 0) * 64 + ln];
  wE[1] = Wf[cL0 + (wv * 2 + 1) * 64 + ln];
  #pragma unroll
  for (int k = 0; k < 4; ++k) {
    wE[2 + k] = Wf[cL1 + (wv * 4 + k) * 64 + ln];
    wP1[k] = Wf[cL3 + (wv * 4 + k) * 64 + ln];
    wD1[k] = Wf[cL6 + (wv * 4 + k) * 64 + ln];
    w7[k]  = Wf[cL7 + (wq * 4 + k) * 64 + ln];
  }
  {
    int base2 = (wv < 4) ? cL2 : cL4;
    #pragma unroll
    for (int k = 0; k < 4; ++k) {
      wmu[k] = Wf[base2 + (wq * 4 + k) * 64 + ln];
      wsd[k] = Wf[base2 + ((wq + 4) * 4 + k) * 64 + ln];
    }
  }
  w5[0] = Wf[cL5 + (wv * 2 + 0) * 64 + ln];
  w5[1] = Wf[cL5 + (wv * 2 + 1) * 64 + ln];
  #pragma unroll
  for (int k = 0; k < 6; ++k) keep(wE[k]);
  #pragma unroll
  for (int k = 0; k < 4; ++k) { keep(wP1[k]); keep(wmu[k]); keep(wsd[k]); keep(wD1[k]); keep(w7[k]); }
  keep(w5[0]); keep(w5[1]);

  float kl_acc = 0.0f, rc_acc = 0.0f;
  __syncthreads();

  const int hm  = tid >> 5;          // h staging: row 0..15
  const int hc4 = (tid & 31) * 4;    // 4 bf16 per thread

  for (int tau = blockIdx.x; tau < TT * 64; tau += gridDim.x) {
    const int t = tau >> 6;
    const int row0 = (tau & 63) * 16;

    // ---- stage h_{t-1}, s_t; load noise ----
    {
      unsigned long long hv = *(const unsigned long long*)(
          hseq + (size_t)t * BB * 128 + (size_t)(row0 + hm) * 128 + hc4);
      *(unsigned long long*)&A_h[hm * 136 + hc4] = hv;
    }
    float2 sv = *(const float2*)(s + ((size_t)t * BB + row0 + pm_) * 64 + pj);
    A_s[pm_ * 72 + pj]     = (bf16_t)sv.x;
    A_s[pm_ * 72 + pj + 1] = (bf16_t)sv.y;
    float nzr[4];
    if (wv < 4) {
      #pragma unroll
      for (int r = 0; r < 4; ++r)
        nzr[r] = noise[((size_t)t * BB + row0 + quad * 4 + r) * 64 + wq * 16 + col];
    }
    wg_barrier();  // B0

    // ---- P1: enc1 + pri1 ----
    bf16x8 ah0 = *(const bf16x8*)&A_h[col * 136 + 0 + quad * 8];
    bf16x8 ah1 = *(const bf16x8*)&A_h[col * 136 + 32 + quad * 8];
    bf16x8 ah2 = *(const bf16x8*)&A_h[col * 136 + 64 + quad * 8];
    bf16x8 ah3 = *(const bf16x8*)&A_h[col * 136 + 96 + quad * 8];
    bf16x8 as0 = *(const bf16x8*)&A_s[col * 72 + 0 + quad * 8];
    bf16x8 as1 = *(const bf16x8*)&A_s[col * 72 + 32 + quad * 8];
    {
      float bv = bsm[nloc0];
      f32x4 c = {bv, bv, bv, bv};
      c = mfma16(as0, wE[0], c);
      c = mfma16(as1, wE[1], c);
      c = mfma16(ah0, wE[2], c);
      c = mfma16(ah1, wE[3], c);
      c = mfma16(ah2, wE[4], c);
      c = mfma16(ah3, wE[5], c);
      #pragma unroll
      for (int r = 0; r < 4; ++r)
        A_e1[(quad * 4 + r) * 136 + nloc0] = (bf16_t)fmaxf(c[r], 0.0f);
    }
    {
      float bv = bsm[128 + nloc0];
      f32x4 c = {bv, bv, bv, bv};
      c = mfma16(ah0, wP1[0], c);
      c = mfma16(ah1, wP1[1], c);
      c = mfma16(ah2, wP1[2], c);
      c = mfma16(ah3, wP1[3], c);
      #pragma unroll
      for (int r = 0; r < 4; ++r)
        A_p1[(quad * 4 + r) * 136 + nloc0] = (bf16_t)fmaxf(c[r], 0.0f);
    }
    wg_barrier();  // B1

    // ---- P2: enc2 (w0-3) -> z + stats; pri2 (w4-7) -> regs ----
    float Pmu[4], Pps[4];
    if (wv < 4) {
      bf16x8 ae0 = *(const bf16x8*)&A_e1[col * 136 + 0 + quad * 8];
      bf16x8 ae1 = *(const bf16x8*)&A_e1[col * 136 + 32 + quad * 8];
      bf16x8 ae2 = *(const bf16x8*)&A_e1[col * 136 + 64 + quad * 8];
      bf16x8 ae3 = *(const bf16x8*)&A_e1[col * 136 + 96 + quad * 8];
      float bm = bsm[256 + wq * 16 + col], bs = bsm[256 + 64 + wq * 16 + col];
      f32x4 cm = {bm, bm, bm, bm};
      f32x4 cs = {bs, bs, bs, bs};
      cm = mfma16(ae0, wmu[0], cm); cs = mfma16(ae0, wsd[0], cs);
      cm = mfma16(ae1, wmu[1], cm); cs = mfma16(ae1, wsd[1], cs);
      cm = mfma16(ae2, wmu[2], cm); cs = mfma16(ae2, wsd[2], cs);
      cm = mfma16(ae3, wmu[3], cm); cs = mfma16(ae3, wsd[3], cs);
      #pragma unroll
      for (int r = 0; r < 4; ++r) {
        float zm = cm[r];
        float zs = softplus_f(cs[r]);
        int m = quad * 4 + r;
        A_z[m * 72 + wq * 16 + col] = (bf16_t)(zm + zs * nzr[r]);
        zmu_s[m * 68 + wq * 16 + col] = zm;
        zsd_s[m * 68 + wq * 16 + col] = zs;
      }
    } else {
      bf16x8 ap0 = *(const bf16x8*)&A_p1[col * 136 + 0 + quad * 8];
      bf16x8 ap1 = *(const bf16x8*)&A_p1[col * 136 + 32 + quad * 8];
      bf16x8 ap2 = *(const bf16x8*)&A_p1[col * 136 + 64 + quad * 8];
      bf16x8 ap3 = *(const bf16x8*)&A_p1[col * 136 + 96 + quad * 8];
      float bm = bsm[384 + wq * 16 + col], bs = bsm[384 + 64 + wq * 16 + col];
      f32x4 cm = {bm, bm, bm, bm};
      f32x4 cs = {bs, bs, bs, bs};
      cm = mfma16(ap0, wmu[0], cm); cs = mfma16(ap0, wsd[0], cs);
      cm = mfma16(ap1, wmu[1], cm); cs = mfma16(ap1, wsd[1], cs);
      cm = mfma16(ap2, wmu[2], cm); cs = mfma16(ap2, wsd[2], cs);
      cm = mfma16(ap3, wmu[3], cm); cs = mfma16(ap3, wsd[3], cs);
      #pragma unroll
      for (int r = 0; r < 4; ++r) { Pmu[r] = cm[r]; Pps[r] = softplus_f(cs[r]); }
    }
    wg_barrier();  // B2

    // ---- P3: dec1 (all waves); KL (w4-7) ----
    {
      bf16x8 az0 = *(const bf16x8*)&A_z[col * 72 + 0 + quad * 8];
      bf16x8 az1 = *(const bf16x8*)&A_z[col * 72 + 32 + quad * 8];
      float bv = bsm[512 + nloc0];
      f32x4 c = {bv, bv, bv, bv};
      c = mfma16(az0, w5[0], c);
      c = mfma16(az1, w5[1], c);
      c = mfma16(ah0, wD1[0], c);
      c = mfma16(ah1, wD1[1], c);
      c = mfma16(ah2, wD1[2], c);
      c = mfma16(ah3, wD1[3], c);
      #pragma unroll
      for (int r = 0; r < 4; ++r)
        A_d1[(quad * 4 + r) * 136 + nloc0] = (bf16_t)fmaxf(c[r], 0.0f);
    }
    if (wv >= 4) {
      #pragma unroll
      for (int r = 0; r < 4; ++r) {
        int m = quad * 4 + r;
        float zm = zmu_s[m * 68 + wq * 16 + col];
        float zs = zsd_s[m * 68 + wq * 16 + col];
        float dm = zm - Pmu[r];
        float ps = Pps[r];
        float den = __expf(2.0f * ps) - 1.0f;
        kl_acc += 0.5f * (2.0f * __logf(ps + 0.01f) - 2.0f * __logf(zs + 0.01f)
                          + (zs * zs + dm * dm) / den);
      }
    }
    wg_barrier();  // B3

    // ---- P4: dec2 (w4-7) -> recon ----
    if (wv >= 4) {
      bf16x8 ad0 = *(const bf16x8*)&A_d1[col * 136 + 0 + quad * 8];
      bf16x8 ad1 = *(const bf16x8*)&A_d1[col * 136 + 32 + quad * 8];
      bf16x8 ad2 = *(const bf16x8*)&A_d1[col * 136 + 64 + quad * 8];
      bf16x8 ad3 = *(const bf16x8*)&A_d1[col * 136 + 96 + quad * 8];
      float bv = bsm[640 + wq * 16 + col];
      f32x4 c = {bv, bv, bv, bv};
      c = mfma16(ad0, w7[0], c);
      c = mfma16(ad1, w7[1], c);
      c = mfma16(ad2, w7[2], c);
      c = mfma16(ad3, w7[3], c);
      #pragma unroll
      for (int r = 0; r < 4; ++r)
        dec2o[(quad * 4 + r) * 68 + wq * 16 + col] = c[r];
    }
    wg_barrier();  // B4
    {
      float d0 = dec2o[pm_ * 68 + pj] - sv.x;
      float d1 = dec2o[pm_ * 68 + pj + 1] - sv.y;
      rc_acc += 0.5f * (d0 * d0 + d1 * d1);
    }
  }

  float tot = (kl_acc + rc_acc) * (1.0f / 1024.0f);
  #pragma unroll
  for (int off = 32; off > 0; off >>= 1) tot += __shfl_down(tot, off);
  if (ln == 0) red[wv] = tot;
  __syncthreads();
  if (tid == 0) {
    float sum = 0.f;
    #pragma unroll
    for (int i = 0; i < 8; ++i) sum += red[i];
    atomicAdd(out, sum);
  }
}

// ---------------- fallback monolith (R2, known-pass) if ws is too small ------------------
__global__ __launch_bounds__(512, 2) void vrnn_mono(
    const float* __restrict__ s, const float* __restrict__ noise,
    const bf16_t* __restrict__ packed, const float* __restrict__ fbias,
    const float* __restrict__ bp1, const float* __restrict__ bp2,
    const float* __restrict__ be2, const float* __restrict__ bd2,
    float* __restrict__ out) {
  const bf16x8* Wf = (const bf16x8*)packed;
  __shared__ __align__(16) bf16_t A_h[16 * 136];
  __shared__ __align__(16) bf16_t A_s[2][16 * 72];
  __shared__ __align__(16) bf16_t A_z[16 * 72];
  __shared__ __align__(16) bf16_t A_e1[16 * 136];
  __shared__ __align__(16) bf16_t A_p1[16 * 136];
  __shared__ __align__(16) bf16_t A_d1[16 * 136];
  __shared__ float zmu_s[16 * 68], zsd_s[16 * 68];
  __shared__ float dec2o[16 * 68];
  __shared__ float bsm[1216];
  __shared__ float red[8];
  const int tid  = threadIdx.x;
  const int wv   = tid >> 6, ln = tid & 63;
  const int quad = ln >> 4, col = ln & 15;
  const int row0 = blockIdx.x * 16;
  const int pm_  = tid >> 5;
  const int pj   = (tid & 31) * 2;
  const int nloc0 = wv * 16 + col;
  const int j_own = wv * 16 + col;
  const int wq   = wv & 3;
  for (int i = tid; i < 1216; i += 512) {
    float v;
    if      (i < 128)  v = fbias[i];
    else if (i < 256)  v = bp1[i - 128];
    else if (i < 384)  v = be2[i - 256];
    else if (i < 512)  v = bp2[i - 384];
    else if (i < 640)  v = fbias[128 + (i - 512)];
    else if (i < 704)  v = bd2[i - 640];
    else               v = fbias[256 + (i - 704)];
    bsm[i] = v;
  }
  for (int i = tid; i < 16 * 136; i += 512) A_h[i] = (bf16_t)0.0f;
  {
    float2 v = *(const float2*)(s + ((size_t)0 * BB + row0 + pm_) * 64 + pj);
    A_s[0][pm_ * 72 + pj]     = (bf16_t)v.x;
    A_s[0][pm_ * 72 + pj + 1] = (bf16_t)v.y;
  }
  bf16x8 rb9[4][2], rb10[4][4];
  #pragma unroll
  for (int i = 0; i < 4; ++i) {
    int nt = wv + 8 * i;
    rb9[i][0] = Wf[cL9 + (nt * 2 + 0) * 64 + ln];
    rb9[i][1] = Wf[cL9 + (nt * 2 + 1) * 64 + ln];
    #pragma unroll
    for (int k = 0; k < 4; ++k) rb10[i][k] = Wf[cL10 + (nt * 4 + k) * 64 + ln];
  }
  bf16x8 wE0[2], wE1[4];
  wE0[0] = Wf[cL0 + (wv * 2 + 0) * 64 + ln];
  wE0[1] = Wf[cL0 + (wv * 2 + 1) * 64 + ln];
  #pragma unroll
  for (int k = 0; k < 4; ++k) wE1[k] = Wf[cL1 + (wv * 4 + k) * 64 + ln];
  bf16x8 wmu[4], wsd[4];
  {
    int base2 = (wv < 4) ? cL2 : cL4;
    #pragma unroll
    for (int k = 0; k < 4; ++k) {
      wmu[k] = Wf[base2 + (wq * 4 + k) * 64 + ln];
      wsd[k] = Wf[base2 + ((wq + 4) * 4 + k) * 64 + ln];
    }
  }
  f32x4 c_reg = {0.f, 0.f, 0.f, 0.f};
  float kl_acc = 0.0f, rc_acc = 0.0f;
  __syncthreads();
  for (int t = 0; t < TT; ++t) {
    const int sb = t & 1;
    float nzr[4];
    if (wv < 4) {
      #pragma unroll
      for (int r = 0; r < 4; ++r)
        nzr[r] = noise[((size_t)t * BB + row0 + quad * 4 + r) * 64 + j_own];
    }
    float2 svv = make_float2(0.f, 0.f);
    if (t + 1 < TT) svv = *(const float2*)(s + ((size_t)(t + 1) * BB + row0 + pm_) * 64 + pj);
    float2 spv = make_float2(0.f, 0.f);
    if (t > 0) spv = *(const float2*)(s + ((size_t)(t - 1) * BB + row0 + pm_) * 64 + pj);
    bf16x8 w8[4][2], wP1[4], wD1[4];
    #pragma unroll
    for (int i = 0; i < 4; ++i) {
      int nt = wv + 8 * i;
      w8[i][0] = Wf[cL8 + (nt * 2 + 0) * 64 + ln];
      w8[i][1] = Wf[cL8 + (nt * 2 + 1) * 64 + ln];
    }
    #pragma unroll
    for (int k = 0; k < 4; ++k) {
      wP1[k] = Wf[cL3 + (wv * 4 + k) * 64 + ln];
      wD1[k] = Wf[cL6 + (wv * 4 + k) * 64 + ln];
    }
    bf16x8 ah0 = *(const bf16x8*)&A_h[col * 136 + 0 + quad * 8];
    bf16x8 ah1 = *(const bf16x8*)&A_h[col * 136 + 32 + quad * 8];
    bf16x8 ah2 = *(const bf16x8*)&A_h[col * 136 + 64 + quad * 8];
    bf16x8 ah3 = *(const bf16x8*)&A_h[col * 136 + 96 + quad * 8];
    bf16x8 as0 = *(const bf16x8*)&A_s[sb][col * 72 + 0 + quad * 8];
    bf16x8 as1 = *(const bf16x8*)&A_s[sb][col * 72 + 32 + quad * 8];
    {
      float bv = bsm[nloc0];
      f32x4 c = {bv, bv, bv, bv};
      c = mfma16(as0, wE0[0], c);
      c = mfma16(as1, wE0[1], c);
      c = mfma16(ah0, wE1[0], c);
      c = mfma16(ah1, wE1[1], c);
      c = mfma16(ah2, wE1[2], c);
      c = mfma16(ah3, wE1[3], c);
      #pragma unroll
      for (int r = 0; r < 4; ++r)
        A_e1[(quad * 4 + r) * 136 + nloc0] = (bf16_t)fmaxf(c[r], 0.0f);
    }
    f32x4 Cg[4];
    #pragma unroll
    for (int i = 0; i < 4; ++i) {
      float bv = bsm[704 + j_own + 128 * i];
      f32x4 cc = {bv, bv, bv, bv};
      cc = mfma16(ah0, rb10[i][0], cc);
      cc = mfma16(ah1, rb10[i][1], cc);
      cc = mfma16(ah2, rb10[i][2], cc);
      cc = mfma16(ah3, rb10[i][3], cc);
      cc = mfma16(as0, w8[i][0], cc);
      cc = mfma16(as1, w8[i][1], cc);
      Cg[i] = cc;
    }
    {
      float bv = bsm[128 + nloc0];
      f32x4 c = {bv, bv, bv, bv};
      c = mfma16(ah0, wP1[0], c);
      c = mfma16(ah1, wP1[1], c);
      c = mfma16(ah2, wP1[2], c);
      c = mfma16(ah3, wP1[3], c);
      #pragma unroll
      for (int r = 0; r < 4; ++r)
        A_p1[(quad * 4 + r) * 136 + nloc0] = (bf16_t)fmaxf(c[r], 0.0f);
    }
    f32x4 Cd;
    {
      float bv = bsm[512 + nloc0];
      f32x4 c = {bv, bv, bv, bv};
      c = mfma16(ah0, wD1[0], c);
      c = mfma16(ah1, wD1[1], c);
      c = mfma16(ah2, wD1[2], c);
      c = mfma16(ah3, wD1[3], c);
      Cd = c;
    }
    if (wv >= 4 && t > 0) {
      bf16x8 ad0 = *(const bf16x8*)&A_d1[col * 136 + 0 + quad * 8];
      bf16x8 ad1 = *(const bf16x8*)&A_d1[col * 136 + 32 + quad * 8];
      bf16x8 ad2 = *(const bf16x8*)&A_d1[col * 136 + 64 + quad * 8];
      bf16x8 ad3 = *(const bf16x8*)&A_d1[col * 136 + 96 + quad * 8];
      bf16x8 w7[4];
      #pragma unroll
      for (int k = 0; k < 4; ++k) w7[k] = Wf[cL7 + (wq * 4 + k) * 64 + ln];
      float bv = bsm[640 + wq * 16 + col];
      f32x4 c = {bv, bv, bv, bv};
      c = mfma16(ad0, w7[0], c);
      c = mfma16(ad1, w7[1], c);
      c = mfma16(ad2, w7[2], c);
      c = mfma16(ad3, w7[3], c);
      #pragma unroll
      for (int r = 0; r < 4; ++r)
        dec2o[(quad * 4 + r) * 68 + wq * 16 + col] = c[r];
    }
    wg_barrier();
    float Pmu[4], Pps[4];
    if (wv < 4) {
      bf16x8 ae0 = *(const bf16x8*)&A_e1[col * 136 + 0 + quad * 8];
      bf16x8 ae1 = *(const bf16x8*)&A_e1[col * 136 + 32 + quad * 8];
      bf16x8 ae2 = *(const bf16x8*)&A_e1[col * 136 + 64 + quad * 8];
      bf16x8 ae3 = *(const bf16x8*)&A_e1[col * 136 + 96 + quad * 8];
      float bm = bsm[256 + wq * 16 + col], bs = bsm[256 + 64 + wq * 16 + col];
      f32x4 cm = {bm, bm, bm, bm};
      f32x4 cs = {bs, bs, bs, bs};
      cm = mfma16(ae0, wmu[0], cm); cs = mfma16(ae0, wsd[0], cs);
      cm = mfma16(ae1, wmu[1], cm); cs = mfma16(ae1, wsd[1], cs);
      cm = mfma16(ae2, wmu[2], cm); cs = mfma16(ae2, wsd[2], cs);
      cm = mfma16(ae3, wmu[3], cm); cs = mfma16(ae3, wsd[3], cs);
      #pragma unroll
      for (int r = 0; r < 4; ++r) {
        float zm = cm[r];
        float zs = softplus_f(cs[r]);
        float z = zm + zs * nzr[r];
        int m = quad * 4 + r;
        A_z[m * 72 + j_own] = (bf16_t)z;
        zmu_s[m * 68 + j_own] = zm;
        zsd_s[m * 68 + j_own] = zs;
      }
    } else {
      bf16x8 ap0 = *(const bf16x8*)&A_p1[col * 136 + 0 + quad * 8];
      bf16x8 ap1 = *(const bf16x8*)&A_p1[col * 136 + 32 + quad * 8];
      bf16x8 ap2 = *(const bf16x8*)&A_p1[col * 136 + 64 + quad * 8];
      bf16x8 ap3 = *(const bf16x8*)&A_p1[col * 136 + 96 + quad * 8];
      float bm = bsm[384 + wq * 16 + col], bs = bsm[384 + 64 + wq * 16 + col];
      f32x4 cm = {bm, bm, bm, bm};
      f32x4 cs = {bs, bs, bs, bs};
      cm = mfma16(ap0, wmu[0], cm); cs = mfma16(ap0, wsd[0], cs);
      cm = mfma16(ap1, wmu[1], cm); cs = mfma16(ap1, wsd[1], cs);
      cm = mfma16(ap2, wmu[2], cm); cs = mfma16(ap2, wsd[2], cs);
      cm = mfma16(ap3, wmu[3], cm); cs = mfma16(ap3, wsd[3], cs);
      #pragma unroll
      for (int r = 0; r < 4; ++r) { Pmu[r] = cm[r]; Pps[r] = softplus_f(cs[r]); }
    }
    if (t > 0) {
      float d0 = dec2o[pm_ * 68 + pj] - spv.x;
      float d1 = dec2o[pm_ * 68 + pj + 1] - spv.y;
      rc_acc += 0.5f * (d0 * d0 + d1 * d1);
    }
    if (t + 1 < TT) {
      A_s[sb ^ 1][pm_ * 72 + pj]     = (bf16_t)svv.x;
      A_s[sb ^ 1][pm_ * 72 + pj + 1] = (bf16_t)svv.y;
    }
    wg_barrier();
    bf16x8 az0 = *(const bf16x8*)&A_z[col * 72 + 0 + quad * 8];
    bf16x8 az1 = *(const bf16x8*)&A_z[col * 72 + 32 + quad * 8];
    #pragma unroll
    for (int i = 0; i < 4; ++i) {
      Cg[i] = mfma16(az0, rb9[i][0], Cg[i]);
      Cg[i] = mfma16(az1, rb9[i][1], Cg[i]);
    }
    {
      bf16x8 w5a = Wf[cL5 + (wv * 2 + 0) * 64 + ln];
      bf16x8 w5b = Wf[cL5 + (wv * 2 + 1) * 64 + ln];
      Cd = mfma16(az0, w5a, Cd);
      Cd = mfma16(az1, w5b, Cd);
      #pragma unroll
      for (int r = 0; r < 4; ++r)
        A_d1[(quad * 4 + r) * 136 + nloc0] = (bf16_t)fmaxf(Cd[r], 0.0f);
    }
    #pragma unroll
    for (int r = 0; r < 4; ++r) {
      float gi = sigm(Cg[0][r]);
      float gf = sigm(Cg[1][r]);
      float gg = tanh_f(Cg[2][r]);
      float go = sigm(Cg[3][r]);
      float cn = gf * c_reg[r] + gi * gg;
      c_reg[r] = cn;
      A_h[(quad * 4 + r) * 136 + j_own] = (bf16_t)(go * tanh_f(cn));
    }
    if (wv >= 4) {
      #pragma unroll
      for (int r = 0; r < 4; ++r) {
        int m = quad * 4 + r;
        float zm = zmu_s[m * 68 + wq * 16 + col];
        float zs = zsd_s[m * 68 + wq * 16 + col];
        float dm = zm - Pmu[r];
        float ps = Pps[r];
        float den = __expf(2.0f * ps) - 1.0f;
        kl_acc += 0.5f * (2.0f * __logf(ps + 0.01f) - 2.0f * __logf(zs + 0.01f)
                          + (zs * zs + dm * dm) / den);
      }
    }
    wg_barrier();
  }
  if (wv >= 4) {
    bf16x8 ad0 = *(const bf16x8*)&A_d1[col * 136 + 0 + quad * 8];
    bf16x8 ad1 = *(const bf16x8*)&A_d1[col * 136 + 32 + quad * 8];
    bf16x8 ad2 = *(const bf16x8*)&A_d1[col * 136 + 64 + quad * 8];
    bf16x8 ad3 = *(const bf16x8*)&A_d1[col * 136 + 96 + quad * 8];
    bf16x8 w7[4];
    #pragma unroll
    for (int k = 0; k < 4; ++k) w7[k] = Wf[cL7 + (wq * 4 + k) * 64 + ln];
    float bv = bsm[640 + wq * 16 + col];
    f32x4 c = {bv, bv, bv, bv};
    c = mfma16(ad0, w7[0], c);
    c = mfma16(ad1, w7[1], c);
    c = mfma16(ad2, w7[2], c);
    c = mfma16(ad3, w7[3], c);
    #pragma unroll
    for (int r = 0; r < 4; ++r)
      dec2o[(quad * 4 + r) * 68 + wq * 16 + col] = c[r];
  }
  __syncthreads();
  {
    float2 sl = *(const float2*)(s + ((size_t)(TT - 1) * BB + row0 + pm_) * 64 + pj);
    float d0 = dec2o[pm_ * 68 + pj] - sl.x;
    float d1 = dec2o[pm_ * 68 + pj + 1] - sl.y;
    rc_acc += 0.5f * (d0 * d0 + d1 * d1);
  }
  float tot = (kl_acc + rc_acc) * (1.0f / 1024.0f);
  #pragma unroll
  for (int off = 32; off > 0; off >>= 1) tot += __shfl_down(tot, off);
  if (ln == 0) red[wv] = tot;
  __syncthreads();
  if (tid == 0) {
    float sum = 0.f;
    #pragma unroll
    for (int i = 0; i < 8; ++i) sum += red[i];
    atomicAdd(out, sum);
  }
}

extern "C" void kernel_launch(void* const* d_in, const int* in_sizes, int n_in,
                              void* d_out, int out_size, void* d_ws, size_t ws_size,
                              hipStream_t stream) {
  (void)in_sizes; (void)n_in; (void)out_size;
  const float* s   = (const float*)d_in[0];
  const float* nz  = (const float*)d_in[1];
  const float* Wps = (const float*)d_in[2];
  const float* bps = (const float*)d_in[3];
  const float* Wpz = (const float*)d_in[4];
  const float* bpz = (const float*)d_in[5];
  const float* Wp1 = (const float*)d_in[6];
  const float* bp1 = (const float*)d_in[7];
  const float* Wp2 = (const float*)d_in[8];
  const float* bp2 = (const float*)d_in[9];
  const float* We1 = (const float*)d_in[10];
  const float* be1 = (const float*)d_in[11];
  const float* We2 = (const float*)d_in[12];
  const float* be2 = (const float*)d_in[13];
  const float* Wih = (const float*)d_in[14];
  const float* bih = (const float*)d_in[15];
  const float* Whh = (const float*)d_in[16];
  const float* bhh = (const float*)d_in[17];
  const float* Wd1 = (const float*)d_in[18];
  const float* bd1 = (const float*)d_in[19];
  const float* Wd2 = (const float*)d_in[20];
  const float* bd2 = (const float*)d_in[21];

  bf16_t* packed = (bf16_t*)d_ws;
  float* fbias = (float*)((char*)d_ws + WS_FBIAS_OFF);
  float* fold  = (float*)((char*)d_ws + WS_FOLD_OFF);
  bf16_t* hseq = (bf16_t*)((char*)d_ws + WS_HSEQ_OFF);

  hipMemsetAsync(d_out, 0, sizeof(float), stream);
  vrnn_fold<<<(82688 + 255) / 256, 256, 0, stream>>>(We1, Wd1, Wih, Wps, Wpz, bps, bpz,
                                                     be1, bd1, bih, bhh, fold, fbias);
  vrnn_pack<<<(NCHUNK + 255) / 256, 256, 0, stream>>>(fold, We1, We2, Wp1, Wp2, Wd1, Wd2,
                                                      Whh, packed);
  if (ws_size >= WS_NEED) {
    vrnn_loop<<<64, 512, 0, stream>>>(s, nz, packed, fbias, be2, hseq);
    vrnn_tail<<<256, 512, 0, stream>>>(s, nz, packed, fbias, bp1, bp2, be2, bd2, hseq,
                                       (float*)d_out);
  } else {
    vrnn_mono<<<64, 512, 0, stream>>>(s, nz, packed, fbias, bp1, bp2, be2, bd2,
                                      (float*)d_out);
  }
}